// Round 4
// baseline (208.687 us; speedup 1.0000x reference)
//
#include <hip/hip_runtime.h>

#define B_  32
#define C_  256
#define H_  56
#define W_  56
#define HW  3136      // H_*W_
#define KK  9
#define KP  12        // padded taps per plane (48B, 16B-aligned)
#define NPLANES (B_*C_)   // 8192

typedef float v4f __attribute__((ext_vector_type(4)));

// ---------------------------------------------------------------------------
// Kernel 1: global average pool. One WAVE per (b,c) plane, 4 planes/block.
// Pure shuffle reduction; regular loads keep x resident in L3 for dconv.
// At the HBM read floor (~17 us) — unchanged.
// ---------------------------------------------------------------------------
__global__ __launch_bounds__(256) void pool_kernel(const float* __restrict__ x,
                                                   float* __restrict__ pooled) {
    const int wid  = threadIdx.x >> 6;
    const int lane = threadIdx.x & 63;
    const int plane = blockIdx.x * 4 + wid;             // 2048 blocks * 4 waves
    const float4* xp = (const float4*)(x + (size_t)plane * HW);

    float s = 0.f;
    #pragma unroll
    for (int k = 0; k < 12; ++k) {                      // 12*64 = 768 strips
        float4 v = xp[lane + k * 64];
        s += (v.x + v.y) + (v.z + v.w);
    }
    if (lane < 16) {                                    // remainder 768..783
        float4 v = xp[768 + lane];
        s += (v.x + v.y) + (v.z + v.w);
    }
    #pragma unroll
    for (int off = 32; off > 0; off >>= 1)
        s += __shfl_down(s, off, 64);
    if (lane == 0)
        pooled[plane] = s * (1.0f / (float)HW);
}

// ---------------------------------------------------------------------------
// Kernel 2 (new): kernel generation for ALL planes, once.
// One block per plane, 192 threads (144 active): tap o = t/16, 16 lanes x
// 16-channel partial dots, shuffle-reduced. Removes the per-block serial
// kerngen prologue + barrier from dconv and the x32-redundant Wk re-read
// from its critical path.
// ---------------------------------------------------------------------------
__global__ __launch_bounds__(192) void kgen_kernel(const float* __restrict__ pooled,
                                                   const float* __restrict__ Wk,
                                                   const float* __restrict__ bk,
                                                   float* __restrict__ kern) {
    const int plane = blockIdx.x;                       // b*C_ + c
    const int b = plane >> 8;
    const int c = plane & 255;
    const int t = threadIdx.x;
    if (t < 144) {
        const int o  = t >> 4;                          // 0..8
        const int ch = (t & 15) << 4;                   // 0,16,...,240
        const int og = c * KK + o;                      // row of Wk
        const float4* wr = (const float4*)(Wk + (size_t)og * C_ + ch);
        const float4* pr = (const float4*)(pooled + b * C_ + ch);
        float s = 0.f;
        #pragma unroll
        for (int i = 0; i < 4; ++i) {
            float4 w = wr[i];
            float4 p = pr[i];
            s += w.x * p.x + w.y * p.y + w.z * p.z + w.w * p.w;
        }
        #pragma unroll
        for (int off = 8; off > 0; off >>= 1)           // reduce 16-lane groups
            s += __shfl_down(s, off, 16);
        if ((t & 15) == 0)
            kern[(size_t)plane * KP + o] = fmaxf(s + bk[og], 0.f);
    }
}

// ---------------------------------------------------------------------------
// Kernel 3: pure register stencil. No LDS, no barrier.
//   * 9 taps: 3 block-uniform dwordx4 loads -> readfirstlane -> SGPRs.
//     Every wave starts stencil work immediately; taps cost 0 VGPRs.
//   * tile map: lane=(g,k), k<14 active, rp = half*16 + wave*4 + g.
//     Left/right halos via __shfl_up/down(.,1,16) (DPP) — zero memory ops.
//   * per 2x4 tile: 4 dwordx4 loads + 8 shuffles; regular stores (L2 merges
//     the even/odd-row split lines).
// ---------------------------------------------------------------------------
__global__ __launch_bounds__(256, 8) void dconv_kernel(const float* __restrict__ x,
                                                       const float* __restrict__ kern,
                                                       float* __restrict__ out) {
    const int plane = blockIdx.x;                       // b*C_ + c
    const int t = threadIdx.x;

    // Block-uniform tap load -> SGPRs.
    const float4* kp = (const float4*)(kern + (size_t)plane * KP);
    float4 k0 = kp[0], k1 = kp[1], k2 = kp[2];
    const float w0 = __int_as_float(__builtin_amdgcn_readfirstlane(__float_as_int(k0.x)));
    const float w1 = __int_as_float(__builtin_amdgcn_readfirstlane(__float_as_int(k0.y)));
    const float w2 = __int_as_float(__builtin_amdgcn_readfirstlane(__float_as_int(k0.z)));
    const float w3 = __int_as_float(__builtin_amdgcn_readfirstlane(__float_as_int(k0.w)));
    const float w4 = __int_as_float(__builtin_amdgcn_readfirstlane(__float_as_int(k1.x)));
    const float w5 = __int_as_float(__builtin_amdgcn_readfirstlane(__float_as_int(k1.y)));
    const float w6 = __int_as_float(__builtin_amdgcn_readfirstlane(__float_as_int(k1.z)));
    const float w7 = __int_as_float(__builtin_amdgcn_readfirstlane(__float_as_int(k1.w)));
    const float w8 = __int_as_float(__builtin_amdgcn_readfirstlane(__float_as_int(k2.x)));

    const float* xp = x + (size_t)plane * HW;
    float* op = out + (size_t)plane * HW;

    const int lane = t & 63;
    const int k    = lane & 15;                         // column group: k*4
    const int g    = lane >> 4;                         // row-pair group in wave
    const int wv   = t >> 6;                            // wave id 0..3
    const bool ka  = (k < 14);                          // cols 0..55
    const int c0   = ka ? (k << 2) : 0;                 // clamp idle lanes in-bounds
    const bool hl  = (k > 0);                           // has in-row left neighbor
    const bool hr  = (k < 13);                          // has in-row right neighbor

    #pragma unroll
    for (int half = 0; half < 2; ++half) {
        const int rp = half * 16 + wv * 4 + g;          // 0..15, then 16..31
        if (rp >= 28) break;                            // wave-uniform (wv=3,half=1)

        const int rA = (rp == 0)  ? 0  : 2 * rp - 1;    // row above (clamped)
        const int rB = (rp == 27) ? 55 : 2 * rp + 2;    // row below (clamped)

        float4 A  = *(const float4*)(xp + rA * W_ + c0);
        float4 M  = *(const float4*)(xp + (2 * rp) * W_ + c0);
        float4 N  = *(const float4*)(xp + (2 * rp + 1) * W_ + c0);
        float4 Bv = *(const float4*)(xp + rB * W_ + c0);
        if (rp == 0)  { A.x = 0.f;  A.y = 0.f;  A.z = 0.f;  A.w = 0.f; }
        if (rp == 27) { Bv.x = 0.f; Bv.y = 0.f; Bv.z = 0.f; Bv.w = 0.f; }

        if (ka) {
            // halo columns from neighbor lanes (16-lane groups => DPP)
            float Al = __shfl_up(A.w, 1, 16),  Ar = __shfl_down(A.x, 1, 16);
            float Ml = __shfl_up(M.w, 1, 16),  Mr = __shfl_down(M.x, 1, 16);
            float Nl = __shfl_up(N.w, 1, 16),  Nr = __shfl_down(N.x, 1, 16);
            float Bl = __shfl_up(Bv.w, 1, 16), Br = __shfl_down(Bv.x, 1, 16);
            Al = hl ? Al : 0.f;  Ml = hl ? Ml : 0.f;
            Nl = hl ? Nl : 0.f;  Bl = hl ? Bl : 0.f;
            Ar = hr ? Ar : 0.f;  Mr = hr ? Mr : 0.f;
            Nr = hr ? Nr : 0.f;  Br = hr ? Br : 0.f;

            v4f t0, t1;
            t0.x = w0*Al  + w1*A.x  + w2*A.y  + w3*Ml  + w4*M.x  + w5*M.y  + w6*Nl  + w7*N.x  + w8*N.y;
            t0.y = w0*A.x + w1*A.y  + w2*A.z  + w3*M.x + w4*M.y  + w5*M.z  + w6*N.x + w7*N.y  + w8*N.z;
            t0.z = w0*A.y + w1*A.z  + w2*A.w  + w3*M.y + w4*M.z  + w5*M.w  + w6*N.y + w7*N.z  + w8*N.w;
            t0.w = w0*A.z + w1*A.w  + w2*Ar   + w3*M.z + w4*M.w  + w5*Mr   + w6*N.z + w7*N.w  + w8*Nr;
            t1.x = w0*Ml  + w1*M.x  + w2*M.y  + w3*Nl  + w4*N.x  + w5*N.y  + w6*Bl  + w7*Bv.x + w8*Bv.y;
            t1.y = w0*M.x + w1*M.y  + w2*M.z  + w3*N.x + w4*N.y  + w5*N.z  + w6*Bv.x+ w7*Bv.y + w8*Bv.z;
            t1.z = w0*M.y + w1*M.z  + w2*M.w  + w3*N.y + w4*N.z  + w5*N.w  + w6*Bv.y+ w7*Bv.z + w8*Bv.w;
            t1.w = w0*M.z + w1*M.w  + w2*Mr   + w3*N.z + w4*N.w  + w5*Nr   + w6*Bv.z+ w7*Bv.w + w8*Br;

            *(v4f*)(op + (2 * rp + 0) * W_ + c0) = t0;  // regular stores: L2 merges
            *(v4f*)(op + (2 * rp + 1) * W_ + c0) = t1;
        }
    }
}

extern "C" void kernel_launch(void* const* d_in, const int* in_sizes, int n_in,
                              void* d_out, int out_size, void* d_ws, size_t ws_size,
                              hipStream_t stream) {
    const float* x  = (const float*)d_in[0];   // [B,C,H,W]
    const float* Wk = (const float*)d_in[1];   // [C*K*K, C]
    const float* bk = (const float*)d_in[2];   // [C*K*K]
    float* out = (float*)d_out;                // [B,C,H,W]

    float* pooled = (float*)d_ws;              // B*C = 8192 floats
    float* kern   = pooled + NPLANES;          // NPLANES*KP floats (384 KB)

    pool_kernel<<<NPLANES / 4, 256, 0, stream>>>(x, pooled);
    kgen_kernel<<<NPLANES, 192, 0, stream>>>(pooled, Wk, bk, kern);
    dconv_kernel<<<NPLANES, 256, 0, stream>>>(x, kern, out);
}